// Round 16
// baseline (3476.545 us; speedup 1.0000x reference)
//
#include <hip/hip_runtime.h>
#include <hip/hip_cooperative_groups.h>

namespace cg = cooperative_groups;

#define B_ 128
#define K_ 25
#define DEG_ 16

#define R4(X) X(0) X(1) X(2) X(3)

typedef __attribute__((ext_vector_type(4))) float f32x4;
typedef __attribute__((ext_vector_type(8))) short bf16x8;

__device__ __forceinline__ float4 f4ma(float t, float4 w, float4 a) {
    a.x = fmaf(t, w.x, a.x); a.y = fmaf(t, w.y, a.y);
    a.z = fmaf(t, w.z, a.z); a.w = fmaf(t, w.w, a.w);
    return a;
}
__device__ __forceinline__ float4 f4max(float4 a, float4 b) {
    return make_float4(fmaxf(a.x, b.x), fmaxf(a.y, b.y), fmaxf(a.z, b.z), fmaxf(a.w, b.w));
}
__device__ __forceinline__ float4 f4add(float4 a, float4 b) {
    return make_float4(a.x + b.x, a.y + b.y, a.z + b.z, a.w + b.w);
}
__device__ __forceinline__ float4 f4sub2(float4 s, float4 p) {
    return make_float4(2.f * s.x - p.x, 2.f * s.y - p.y, 2.f * s.z - p.z, 2.f * s.w - p.w);
}
// bf16 pack (RTNE)
__device__ __forceinline__ unsigned f2bfu(float f) {
    unsigned u = __float_as_uint(f);
    return (u + 0x7FFFu + ((u >> 16) & 1u)) >> 16;
}
__device__ __forceinline__ unsigned packbf(float e, float o) { return f2bfu(e) | (f2bfu(o) << 16); }
__device__ __forceinline__ float4 mevens(uint4 m) {
    return make_float4(__uint_as_float(m.x << 16), __uint_as_float(m.y << 16),
                       __uint_as_float(m.z << 16), __uint_as_float(m.w << 16));
}
__device__ __forceinline__ float4 modds(uint4 m) {
    return make_float4(__uint_as_float(m.x & 0xFFFF0000u), __uint_as_float(m.y & 0xFFFF0000u),
                       __uint_as_float(m.z & 0xFFFF0000u), __uint_as_float(m.w & 0xFFFF0000u));
}

__device__ __forceinline__ bf16x8 u2b(uint4 u) {
    union { uint4 u4; bf16x8 b8; } c; c.u4 = u; return c.b8;
}
__device__ __forceinline__ f32x4 mfma_bf(uint4 a, uint4 b, f32x4 c) {
    return __builtin_amdgcn_mfma_f32_16x16x32_bf16(u2b(a), u2b(b), c, 0, 0, 0);
}

// ---------------- transpose x -> x0 (4096,128) + T0 bf16 mirror
__global__ __launch_bounds__(256) void k_transpose_xm(const float* __restrict__ x,
        float* __restrict__ x0, unsigned* __restrict__ mir) {
    int i = blockIdx.x * 256 + threadIdx.x;   // i = v*64 + bp
    int v = i >> 6, bp = i & 63;
    float e = x[((size_t)(2 * bp) << 12) + v];
    float o = x[((size_t)(2 * bp + 1) << 12) + v];
    x0[(v << 7) + 2 * bp] = e;
    x0[(v << 7) + 2 * bp + 1] = o;
    mir[(v << 6) + bp] = packbf(e, o);
}

// ---------------- prepack W2/W3 -> bf16 [k][fo][fi]
__global__ __launch_bounds__(256) void k_packw(const float* __restrict__ w2, const float* __restrict__ w3,
        unsigned short* __restrict__ wb2, unsigned short* __restrict__ wb3) {
    int i = blockIdx.x * 256 + threadIdx.x;
    if (i < 51200) {
        int k = i >> 11, rem = i & 2047, fo = rem >> 5, fi = rem & 31;
        wb2[i] = (unsigned short)f2bfu(w2[(size_t)(fi * K_ + k) * 64 + fo]);
    }
    if (i < 102400) {
        int k = i >> 12, rem = i & 4095, fo = rem >> 6, fi = rem & 63;
        wb3[i] = (unsigned short)f2bfu(w3[(size_t)(fi * K_ + k) * 64 + fo]);
    }
}

// ---------------- layer-1 full chain (cooperative): 24 steps, 256 blocks
__global__ __launch_bounds__(256) void k_chain1(const int* __restrict__ cols, const float* __restrict__ vals,
        float* __restrict__ basis1, unsigned* __restrict__ mir) {
    cg::grid_group grid = cg::this_grid();
    const size_t S1 = 4096 * 128;
    int i = blockIdx.x * 256 + threadIdx.x;   // 65536: v = i>>4, sl = i&15
    int v = i >> 4, sl = i & 15;
    int base = v * DEG_;
    int moff = sl << 2;
    // hoist sparse row (constant across steps)
    const int4* cp = (const int4*)(cols + base);
    const float4* vp = (const float4*)(vals + base);
    int4 c0 = cp[0], c1 = cp[1], c2 = cp[2], c3 = cp[3];
    float4 w0 = vp[0], w1 = vp[1], w2 = vp[2], w3 = vp[3];
    for (int k = 1; k < 25; ++k) {
        const unsigned* mirPrev = mir + (size_t)((k - 1) & 1) * (S1 / 2);
        unsigned* mirOut = mir + (size_t)(k & 1) * (S1 / 2);
        const float* prevF = basis1 + (size_t)(k >= 2 ? k - 2 : 0) * S1;
        float* nextF = basis1 + (size_t)k * S1;
        float4 eA = make_float4(0.f, 0.f, 0.f, 0.f), oA = eA, eB = eA, oB = eA;
#define G1(cc, ww) { \
        uint4 m = *(const uint4*)(mirPrev + ((size_t)(cc) << 6) + moff); \
        eA = f4ma((ww), mevens(m), eA); oA = f4ma((ww), modds(m), oA); }
#define G2(cc, ww) { \
        uint4 m = *(const uint4*)(mirPrev + ((size_t)(cc) << 6) + moff); \
        eB = f4ma((ww), mevens(m), eB); oB = f4ma((ww), modds(m), oB); }
        G1(c0.x, w0.x) G1(c0.y, w0.y) G1(c0.z, w0.z) G1(c0.w, w0.w)
        G1(c1.x, w1.x) G1(c1.y, w1.y) G1(c1.z, w1.z) G1(c1.w, w1.w)
        G2(c2.x, w2.x) G2(c2.y, w2.y) G2(c2.z, w2.z) G2(c2.w, w2.w)
        G2(c3.x, w3.x) G2(c3.y, w3.y) G2(c3.z, w3.z) G2(c3.w, w3.w)
#undef G1
#undef G2
        float4 e = f4add(eA, eB), o = f4add(oA, oB);
        float4 f0 = make_float4(e.x, o.x, e.y, o.y);
        float4 f1 = make_float4(e.z, o.z, e.w, o.w);
        size_t sidx = ((size_t)v << 7) + (sl << 3);
        if (k >= 2) {
            float4 p0 = *(const float4*)(prevF + sidx), p1 = *(const float4*)(prevF + sidx + 4);
            f0 = f4sub2(f0, p0); f1 = f4sub2(f1, p1);
        }
        *(float4*)(nextF + sidx) = f0;
        *(float4*)(nextF + sidx + 4) = f1;
        *(uint4*)(mirOut + ((size_t)v << 6) + moff) =
            make_uint4(packbf(f0.x, f0.y), packbf(f0.z, f0.w), packbf(f1.x, f1.y), packbf(f1.z, f1.w));
        if (k < 24) grid.sync();
    }
}

// ---------------- layer-2 fused chain group (cooperative): 512 blocks x 4 tiles, nsteps steps
__global__ __launch_bounds__(256) void k_chain2g(const int* __restrict__ cols, const float* __restrict__ vals,
        float* __restrict__ stA, float* __restrict__ stB, unsigned* __restrict__ mir,
        int k0, int nsteps) {
    cg::grid_group grid = cg::this_grid();
    int xcd = blockIdx.x & 7, q0 = blockIdx.x >> 3;   // q0 in [0,64)
    int l = threadIdx.x & 63;
    int vloc = threadIdx.x >> 6;                      // 0..3
    int cc = (xcd << 6) + l;
    int fi2 = cc >> 5, b0 = (cc & 31) << 2;
    int moff = (fi2 << 7) + b0;
    for (int step = 0; step < nsteps; ++step) {
        int k = k0 + step;
        const unsigned* mirPrev = mir + (size_t)((k - 1) % 5) * 2097152;
        unsigned* mirOut = mir + (size_t)(k % 5) * 2097152;
        float* st = (k & 1) ? stB : stA;
        int two = (k >= 2);
#pragma unroll
        for (int t = 0; t < 4; ++t) {
            int q = q0 + (t << 6);
            int v = __builtin_amdgcn_readfirstlane((q << 2) + vloc);
            int base = v * DEG_;
            float4 eA = make_float4(0.f, 0.f, 0.f, 0.f), eB = eA, oA = eA, oB = eA;
#pragma unroll
            for (int d = 0; d < 8; ++d) {
                {
                    float w = vals[base + d];
                    uint4 m = *(const uint4*)(mirPrev + (size_t)cols[base + d] * 2048 + moff);
                    eA = f4ma(w, mevens(m), eA); oA = f4ma(w, modds(m), oA);
                }
                {
                    float w = vals[base + 8 + d];
                    uint4 m = *(const uint4*)(mirPrev + (size_t)cols[base + 8 + d] * 2048 + moff);
                    eB = f4ma(w, mevens(m), eB); oB = f4ma(w, modds(m), oB);
                }
            }
            float4 e = f4add(eA, eB), o = f4add(oA, oB);
            size_t sidx = ((size_t)v << 12) + (fi2 << 8) + b0;
            if (two) {
                float4 pe = *(const float4*)(st + sidx), po = *(const float4*)(st + sidx + 128);
                e = f4sub2(e, pe); o = f4sub2(o, po);
            }
            *(float4*)(st + sidx) = e;
            *(float4*)(st + sidx + 128) = o;
            *(uint4*)(mirOut + (size_t)v * 2048 + moff) =
                make_uint4(packbf(e.x, o.x), packbf(e.y, o.y), packbf(e.z, o.z), packbf(e.w, o.w));
        }
        if (step < nsteps - 1) grid.sync();
    }
}

// ---------------- layer-3 fused chain group (cooperative): 256 blocks x 4 tiles
__global__ __launch_bounds__(256) void k_chain3g(const int* __restrict__ cols, const float* __restrict__ vals,
        float* __restrict__ stA, float* __restrict__ stB, unsigned* __restrict__ mir,
        int k0, int nsteps) {
    cg::grid_group grid = cg::this_grid();
    int xcd = blockIdx.x & 7, q0 = blockIdx.x >> 3;   // q0 in [0,32)
    int l = threadIdx.x & 127;
    int vloc = threadIdx.x >> 7;                      // 0..1
    int cc = (xcd << 7) + l;
    int fi2 = cc >> 5, b0 = (cc & 31) << 2;
    int moff = (fi2 << 7) + b0;
    for (int step = 0; step < nsteps; ++step) {
        int k = k0 + step;
        const unsigned* mirPrev = mir + (size_t)((k - 1) % 5) * 1048576;
        unsigned* mirOut = mir + (size_t)(k % 5) * 1048576;
        float* st = (k & 1) ? stB : stA;
        int two = (k >= 2);
#pragma unroll
        for (int t = 0; t < 4; ++t) {
            int q = q0 + (t << 5);
            int v = __builtin_amdgcn_readfirstlane((q << 1) + vloc);
            int base = v * DEG_;
            float4 eA = make_float4(0.f, 0.f, 0.f, 0.f), eB = eA, oA = eA, oB = eA;
#pragma unroll
            for (int d = 0; d < 8; ++d) {
                {
                    float w = vals[base + d];
                    uint4 m = *(const uint4*)(mirPrev + (size_t)cols[base + d] * 4096 + moff);
                    eA = f4ma(w, mevens(m), eA); oA = f4ma(w, modds(m), oA);
                }
                {
                    float w = vals[base + 8 + d];
                    uint4 m = *(const uint4*)(mirPrev + (size_t)cols[base + 8 + d] * 4096 + moff);
                    eB = f4ma(w, mevens(m), eB); oB = f4ma(w, modds(m), oB);
                }
            }
            float4 e = f4add(eA, eB), o = f4add(oA, oB);
            size_t sidx = ((size_t)v << 13) + (fi2 << 8) + b0;
            if (two) {
                float4 pe = *(const float4*)(st + sidx), po = *(const float4*)(st + sidx + 128);
                e = f4sub2(e, pe); o = f4sub2(o, po);
            }
            *(float4*)(st + sidx) = e;
            *(float4*)(st + sidx + 128) = o;
            *(uint4*)(mirOut + (size_t)v * 4096 + moff) =
                make_uint4(packbf(e.x, o.x), packbf(e.y, o.y), packbf(e.z, o.z), packbf(e.w, o.w));
        }
        if (step < nsteps - 1) grid.sync();
    }
}

// ---------------- layer 1 projection + bias + relu + pool4 (+ bf16 mirror)
__global__ __launch_bounds__(256) void k_proj1_pool(const float* __restrict__ basis,
        const float* __restrict__ W1, const float* __restrict__ b1, float* __restrict__ pool1,
        unsigned* __restrict__ mir) {
    int half = blockIdx.y;
    int i = blockIdx.x * 256 + threadIdx.x;   // i = g*128 + b
    int g = i >> 7, b = i & 127;
    const float* wbase = W1 + half * 16;
#define P1_DM(j) float4 M##j = make_float4(-1e30f, -1e30f, -1e30f, -1e30f);
    R4(P1_DM)
#undef P1_DM
    for (int r = 0; r < 4; ++r) {
        const float* bp = basis + (((size_t)(4 * g + r) << 7) + b);
#define P1_DC(j) float4 C##j = make_float4(0.f, 0.f, 0.f, 0.f);
        R4(P1_DC)
#undef P1_DC
#pragma unroll 5
        for (int k = 0; k < K_; ++k) {
            float tv = bp[(size_t)k * 524288];
            const float4* w = (const float4*)(wbase + k * 32);
#define P1_FM(j) C##j = f4ma(tv, w[j], C##j);
            R4(P1_FM)
#undef P1_FM
        }
#define P1_MX(j) M##j = f4max(M##j, C##j);
        R4(P1_MX)
#undef P1_MX
    }
    float* op = pool1 + ((size_t)g << 12) + ((size_t)half << 11) + b;
    unsigned* mp = mir + ((size_t)g << 11) + ((size_t)half << 10) + b;
    const float* bb = b1 + half * 16;
#define P1_ST(j) { \
    float e0 = fmaxf(M##j.x + bb[4*j+0], 0.f); \
    float o0 = fmaxf(M##j.y + bb[4*j+1], 0.f); \
    float e1 = fmaxf(M##j.z + bb[4*j+2], 0.f); \
    float o1 = fmaxf(M##j.w + bb[4*j+3], 0.f); \
    op[(4*j+0)*128] = e0; op[(4*j+1)*128] = o0; \
    op[(4*j+2)*128] = e1; op[(4*j+3)*128] = o1; \
    mp[(2*j+0)*128] = packbf(e0, o0); \
    mp[(2*j+1)*128] = packbf(e1, o1); }
    R4(P1_ST)
#undef P1_ST
}

// ---------------- layer-2 chunk projection via MFMA
__global__ __launch_bounds__(256) void k_proj_l2m(const unsigned* __restrict__ mir, size_t slotH,
        const uint4* __restrict__ wb, float* __restrict__ acc, int k0, int init,
        const float* __restrict__ bias) {
    int wid = blockIdx.x * 4 + (threadIdx.x >> 6);
    int lane = threadIdx.x & 63;
    int lm = lane & 15, lg = lane >> 4;
    int v = wid >> 3, b0 = (wid & 7) << 4;
    float* ap = acc + ((size_t)v << 13) + b0 + (lg << 2);
    f32x4 C0, C1, C2, C3;
    if (init) {
        float q0 = bias[lm], q1 = bias[16 + lm], q2 = bias[32 + lm], q3 = bias[48 + lm];
        C0 = f32x4{q0, q0, q0, q0}; C1 = f32x4{q1, q1, q1, q1};
        C2 = f32x4{q2, q2, q2, q2}; C3 = f32x4{q3, q3, q3, q3};
    } else {
        C0 = *(const f32x4*)(ap + (size_t)lm * 128);
        C1 = *(const f32x4*)(ap + (size_t)(16 + lm) * 128);
        C2 = *(const f32x4*)(ap + (size_t)(32 + lm) * 128);
        C3 = *(const f32x4*)(ap + (size_t)(48 + lm) * 128);
    }
    const unsigned* mp0 = mir + ((size_t)v << 11) + (lg << 9) + b0 + lm;
#pragma unroll
    for (int kk = 0; kk < 5; ++kk) {
        const unsigned* mp = mp0 + (size_t)kk * slotH;
        uint4 a = make_uint4(mp[0], mp[128], mp[256], mp[384]);
        int kb = (k0 + kk) << 6;
        uint4 w0 = wb[(kb + lm) * 4 + lg];
        uint4 w1 = wb[(kb + 16 + lm) * 4 + lg];
        uint4 w2 = wb[(kb + 32 + lm) * 4 + lg];
        uint4 w3 = wb[(kb + 48 + lm) * 4 + lg];
        C0 = mfma_bf(a, w0, C0);
        C1 = mfma_bf(a, w1, C1);
        C2 = mfma_bf(a, w2, C2);
        C3 = mfma_bf(a, w3, C3);
    }
    *(f32x4*)(ap + (size_t)lm * 128) = C0;
    *(f32x4*)(ap + (size_t)(16 + lm) * 128) = C1;
    *(f32x4*)(ap + (size_t)(32 + lm) * 128) = C2;
    *(f32x4*)(ap + (size_t)(48 + lm) * 128) = C3;
}

// ---------------- layer-3 chunk projection via MFMA
__global__ __launch_bounds__(256) void k_proj_l3m(const unsigned* __restrict__ mir, size_t slotH,
        const uint4* __restrict__ wb, float* __restrict__ acc, int k0, int init,
        const float* __restrict__ bias, int finalrelu) {
    int wid = blockIdx.x * 4 + (threadIdx.x >> 6);
    int lane = threadIdx.x & 63;
    int lm = lane & 15, lg = lane >> 4;
    int v = wid >> 3, b0 = (wid & 7) << 4;
    float* ap = acc + ((size_t)v << 13) + b0 + (lg << 2);
    f32x4 C0, C1, C2, C3;
    if (init) {
        float q0 = bias[lm], q1 = bias[16 + lm], q2 = bias[32 + lm], q3 = bias[48 + lm];
        C0 = f32x4{q0, q0, q0, q0}; C1 = f32x4{q1, q1, q1, q1};
        C2 = f32x4{q2, q2, q2, q2}; C3 = f32x4{q3, q3, q3, q3};
    } else {
        C0 = *(const f32x4*)(ap + (size_t)lm * 128);
        C1 = *(const f32x4*)(ap + (size_t)(16 + lm) * 128);
        C2 = *(const f32x4*)(ap + (size_t)(32 + lm) * 128);
        C3 = *(const f32x4*)(ap + (size_t)(48 + lm) * 128);
    }
    const unsigned* mp0 = mir + ((size_t)v << 12) + b0 + lm;
#pragma unroll
    for (int kk = 0; kk < 5; ++kk) {
        const unsigned* mp = mp0 + (size_t)kk * slotH;
        int kb = (k0 + kk) << 6;
#pragma unroll
        for (int ks = 0; ks < 2; ++ks) {
            const unsigned* mk = mp + (size_t)((ks << 4) + (lg << 2)) * 128;
            uint4 a = make_uint4(mk[0], mk[128], mk[256], mk[384]);
            int wof = (ks << 2) + lg;
            uint4 w0 = wb[(kb + lm) * 8 + wof];
            uint4 w1 = wb[(kb + 16 + lm) * 8 + wof];
            uint4 w2 = wb[(kb + 32 + lm) * 8 + wof];
            uint4 w3 = wb[(kb + 48 + lm) * 8 + wof];
            C0 = mfma_bf(a, w0, C0);
            C1 = mfma_bf(a, w1, C1);
            C2 = mfma_bf(a, w2, C2);
            C3 = mfma_bf(a, w3, C3);
        }
    }
    if (finalrelu) {
#pragma unroll
        for (int r = 0; r < 4; ++r) {
            C0[r] = fmaxf(C0[r], 0.f); C1[r] = fmaxf(C1[r], 0.f);
            C2[r] = fmaxf(C2[r], 0.f); C3[r] = fmaxf(C3[r], 0.f);
        }
    }
    *(f32x4*)(ap + (size_t)lm * 128) = C0;
    *(f32x4*)(ap + (size_t)(16 + lm) * 128) = C1;
    *(f32x4*)(ap + (size_t)(32 + lm) * 128) = C2;
    *(f32x4*)(ap + (size_t)(48 + lm) * 128) = C3;
}

// ---------------- relu + pool4 + bf16 mirror (layer2 acc -> layer3 T0 state + mirror slot0)
__global__ __launch_bounds__(256) void k_relu_pool_m(const float* __restrict__ acc,
        float* __restrict__ pool, unsigned* __restrict__ mir) {
    int i = blockIdx.x * 256 + threadIdx.x;
    int g = i >> 12, fi2 = (i >> 7) & 31, b = i & 127;
    const float* ap = acc + (((size_t)g << 2) << 13) + (fi2 << 8) + b;
    float me = 0.f, mo = 0.f;
#pragma unroll
    for (int r = 0; r < 4; ++r) {
        me = fmaxf(me, ap[0]); mo = fmaxf(mo, ap[128]);
        ap += 8192;
    }
    size_t po = ((size_t)g << 13) + (fi2 << 8) + b;
    pool[po] = me; pool[po + 128] = mo;
    mir[i] = packbf(me, mo);
}

// ---------------- FC1 partials: rowsplit 64, 8 b's per thread, 2048 blocks (round-13 form)
__global__ __launch_bounds__(256) void k_fc1_part(const float* __restrict__ t3, const float* __restrict__ w,
                           float* __restrict__ part) {
    int blk = blockIdx.x;
    int bg = blk >> 7;
    int rs = (blk >> 1) & 63;
    int j = ((blk & 1) << 8) + threadIdx.x;
    int b0 = bg << 3;
    float a0=0.f,a1=0.f,a2=0.f,a3=0.f,a4=0.f,a5=0.f,a6=0.f,a7=0.f;
    int r0 = rs << 8;
#pragma unroll 4
    for (int row = r0; row < r0 + 256; ++row) {
        float wv = w[((size_t)row << 9) + j];
        const float4* tp = (const float4*)(t3 + ((size_t)row << 7) + b0);
        float4 t0 = tp[0], t1 = tp[1];
        a0 = fmaf(t0.x, wv, a0);
        a1 = fmaf(t0.y, wv, a1);
        a2 = fmaf(t0.z, wv, a2);
        a3 = fmaf(t0.w, wv, a3);
        a4 = fmaf(t1.x, wv, a4);
        a5 = fmaf(t1.y, wv, a5);
        a6 = fmaf(t1.z, wv, a6);
        a7 = fmaf(t1.w, wv, a7);
    }
    float* pp = part + (((size_t)(rs << 7) + b0) << 9) + j;
    pp[0*512]=a0; pp[1*512]=a1; pp[2*512]=a2; pp[3*512]=a3;
    pp[4*512]=a4; pp[5*512]=a5; pp[6*512]=a6; pp[7*512]=a7;
}

__global__ __launch_bounds__(256) void k_fc1_red(const float* __restrict__ part, const float* __restrict__ bias,
                          float* __restrict__ h) {
    int i = blockIdx.x * 256 + threadIdx.x;
    float a = bias[i & 511];
#pragma unroll 8
    for (int rs = 0; rs < 64; ++rs) a += part[((size_t)rs << 16) + i];
    h[i] = a;
}

// ---------------- batchnorm stats
__global__ void k_bnstats(const float* __restrict__ h, float* __restrict__ mv) {
    __shared__ float s1[128], s2[128];
    int j = blockIdx.x, t = threadIdx.x;
    float v = h[(size_t)t * 512 + j];
    s1[t] = v; s2[t] = v * v;
    __syncthreads();
    for (int o = 64; o > 0; o >>= 1) {
        if (t < o) { s1[t] += s1[t + o]; s2[t] += s2[t + o]; }
        __syncthreads();
    }
    if (t == 0) {
        float m = s1[0] * (1.f / 128.f);
        float var = s2[0] * (1.f / 128.f) - m * m;
        mv[j] = m;
        mv[512 + j] = rsqrtf(var + 1e-5f);
    }
}

// ---------------- BN apply + relu + FC2 + log_softmax
__global__ void k_head(const float* __restrict__ h, const float* __restrict__ mv,
                       const float* __restrict__ gamma, const float* __restrict__ beta,
                       const float* __restrict__ w2, const float* __restrict__ b2,
                       float* __restrict__ out) {
    __shared__ float hr[512];
    __shared__ float lg[16];
    int b = blockIdx.x, t = threadIdx.x;   // 64 threads
    for (int j = t; j < 512; j += 64) {
        float x = (h[(size_t)b * 512 + j] - mv[j]) * mv[512 + j] * gamma[j] + beta[j];
        hr[j] = fmaxf(x, 0.f);
    }
    __syncthreads();
    if (t < 10) {
        float a = b2[t];
        for (int j = 0; j < 512; ++j) a += hr[j] * w2[j * 10 + t];
        lg[t] = a;
    }
    __syncthreads();
    if (t == 0) {
        float mx = -1e30f;
        for (int q = 0; q < 10; ++q) mx = fmaxf(mx, lg[q]);
        float sum = 0.f;
        for (int q = 0; q < 10; ++q) sum += expf(lg[q] - mx);
        float ls = logf(sum) + mx;
        for (int q = 0; q < 10; ++q) out[b * 10 + q] = lg[q] - ls;
    }
}

extern "C" void kernel_launch(void* const* d_in, const int* in_sizes, int n_in,
                              void* d_out, int out_size, void* d_ws, size_t ws_size,
                              hipStream_t stream) {
    (void)in_sizes; (void)n_in; (void)out_size; (void)ws_size;
    const float* x      = (const float*)d_in[0];
    const int*   l0cols = (const int*)d_in[2];
    const float* l0vals = (const float*)d_in[3];
    const int*   l2cols = (const int*)d_in[5];
    const float* l2vals = (const float*)d_in[6];
    const int*   l4cols = (const int*)d_in[8];
    const float* l4vals = (const float*)d_in[9];
    const float* w1   = (const float*)d_in[10];
    const float* b1   = (const float*)d_in[11];
    const float* w2   = (const float*)d_in[12];
    const float* b2   = (const float*)d_in[13];
    const float* w3   = (const float*)d_in[14];
    const float* b3   = (const float*)d_in[15];
    const float* fc1w = (const float*)d_in[16];
    const float* fc1b = (const float*)d_in[17];
    const float* gam  = (const float*)d_in[18];
    const float* bet  = (const float*)d_in[19];
    const float* fc2w = (const float*)d_in[20];
    const float* fc2b = (const float*)d_in[21];
    float* out = (float*)d_out;

    const size_t S1 = 4096 * 128;
    const size_t S2 = 1024 * 4096;
    const size_t S3 = 256 * 8192;

    float* ws = (float*)d_ws;
    float* basis1 = ws;                                  // 25 slots of S1
    float* st2A   = ws + 25 * S1;
    float* st2B   = st2A + S2;
    unsigned* mir2 = (unsigned*)(st2B + S2);             // 5 slots of S2/2 dwords
    float* tailp  = (float*)(mir2 + 5 * (S2 / 2));
    float* h      = tailp;
    float* mv     = h + 65536;
    unsigned short* wb2 = (unsigned short*)(mv + 1024);
    unsigned short* wb3 = wb2 + 51200;
    unsigned* mir1 = (unsigned*)(wb3 + 102400);          // 2 slots of S1/2 dwords
    float* acc2   = basis1;
    float* st3A   = st2A;
    float* st3B   = st2A + S3;
    float* acc3   = st2B;
    unsigned* mir3 = mir2;
    float* part   = basis1;

    k_packw<<<400, 256, 0, stream>>>(w2, w3, wb2, wb3);

    // ---------------- Layer 1: fused cooperative chain ----------------
    k_transpose_xm<<<1024, 256, 0, stream>>>(x, basis1, mir1);
    {
        void* a[] = {(void*)&l0cols, (void*)&l0vals, (void*)&basis1, (void*)&mir1};
        hipLaunchCooperativeKernel((const void*)k_chain1, dim3(256), dim3(256), a, 0, stream);
    }
    k_proj1_pool<<<dim3(512, 2), 256, 0, stream>>>(basis1, w1, b1, st2A, mir2);

    // ---------------- Layer 2: 5 fused chain groups + proj ----------------
    for (int g2 = 0; g2 < 5; ++g2) {
        int k0 = (g2 == 0) ? 1 : 5 * g2;
        int ns = (g2 == 0) ? 4 : 5;
        void* a[] = {(void*)&l2cols, (void*)&l2vals, (void*)&st2A, (void*)&st2B,
                     (void*)&mir2, (void*)&k0, (void*)&ns};
        hipLaunchCooperativeKernel((const void*)k_chain2g, dim3(512), dim3(256), a, 0, stream);
        k_proj_l2m<<<2048, 256, 0, stream>>>(mir2, S2 / 2, (const uint4*)wb2, acc2, 5 * g2,
                                             g2 == 0 ? 1 : 0, b2);
    }
    k_relu_pool_m<<<4096, 256, 0, stream>>>(acc2, st3A, mir3);

    // ---------------- Layer 3: 5 fused chain groups + proj ----------------
    for (int g3 = 0; g3 < 5; ++g3) {
        int k0 = (g3 == 0) ? 1 : 5 * g3;
        int ns = (g3 == 0) ? 4 : 5;
        void* a[] = {(void*)&l4cols, (void*)&l4vals, (void*)&st3A, (void*)&st3B,
                     (void*)&mir3, (void*)&k0, (void*)&ns};
        hipLaunchCooperativeKernel((const void*)k_chain3g, dim3(256), dim3(256), a, 0, stream);
        k_proj_l3m<<<512, 256, 0, stream>>>(mir3, S3 / 2, (const uint4*)wb3, acc3, 5 * g3,
                                            g3 == 0 ? 1 : 0, b3, g3 == 4 ? 1 : 0);
    }

    // ---------------- FC1 + BN + FC2 + log_softmax ----------------
    k_fc1_part<<<2048, 256, 0, stream>>>(acc3, fc1w, part);
    k_fc1_red<<<256, 256, 0, stream>>>(part, fc1b, h);
    k_bnstats<<<512, 128, 0, stream>>>(h, mv);
    k_head<<<128, 64, 0, stream>>>(h, mv, gam, bet, fc2w, fc2b, out);
}

// Round 17
// 804.544 us; speedup vs baseline: 4.3211x; 4.3211x over previous
//
#include <hip/hip_runtime.h>

#define B_ 128
#define K_ 25
#define DEG_ 16

#define R4(X) X(0) X(1) X(2) X(3)

typedef __attribute__((ext_vector_type(4))) float f32x4;
typedef __attribute__((ext_vector_type(8))) short bf16x8;

__device__ __forceinline__ float4 f4ma(float t, float4 w, float4 a) {
    a.x = fmaf(t, w.x, a.x); a.y = fmaf(t, w.y, a.y);
    a.z = fmaf(t, w.z, a.z); a.w = fmaf(t, w.w, a.w);
    return a;
}
__device__ __forceinline__ float4 f4max(float4 a, float4 b) {
    return make_float4(fmaxf(a.x, b.x), fmaxf(a.y, b.y), fmaxf(a.z, b.z), fmaxf(a.w, b.w));
}
__device__ __forceinline__ float4 f4add(float4 a, float4 b) {
    return make_float4(a.x + b.x, a.y + b.y, a.z + b.z, a.w + b.w);
}
__device__ __forceinline__ float4 f4sub2(float4 s, float4 p) {
    return make_float4(2.f * s.x - p.x, 2.f * s.y - p.y, 2.f * s.z - p.z, 2.f * s.w - p.w);
}
// bf16 pack (RTNE)
__device__ __forceinline__ unsigned f2bfu(float f) {
    unsigned u = __float_as_uint(f);
    return (u + 0x7FFFu + ((u >> 16) & 1u)) >> 16;
}
__device__ __forceinline__ unsigned packbf(float e, float o) { return f2bfu(e) | (f2bfu(o) << 16); }
// mirror dword -> even/odd floats
__device__ __forceinline__ float4 mevens(uint4 m) {
    return make_float4(__uint_as_float(m.x << 16), __uint_as_float(m.y << 16),
                       __uint_as_float(m.z << 16), __uint_as_float(m.w << 16));
}
__device__ __forceinline__ float4 modds(uint4 m) {
    return make_float4(__uint_as_float(m.x & 0xFFFF0000u), __uint_as_float(m.y & 0xFFFF0000u),
                       __uint_as_float(m.z & 0xFFFF0000u), __uint_as_float(m.w & 0xFFFF0000u));
}

__device__ __forceinline__ bf16x8 u2b(uint4 u) {
    union { uint4 u4; bf16x8 b8; } c; c.u4 = u; return c.b8;
}
__device__ __forceinline__ f32x4 mfma_bf(uint4 a, uint4 b, f32x4 c) {
    return __builtin_amdgcn_mfma_f32_16x16x32_bf16(u2b(a), u2b(b), c, 0, 0, 0);
}

// ---------------- transpose x: (B=128, N=4096) -> x0 (4096, 128) + T0 bf16 mirror
__global__ __launch_bounds__(256) void k_transpose_xm(const float* __restrict__ x,
        float* __restrict__ x0, unsigned* __restrict__ mir) {
    int i = blockIdx.x * 256 + threadIdx.x;   // i = v*64 + bp
    int v = i >> 6, bp = i & 63;
    float e = x[((size_t)(2 * bp) << 12) + v];
    float o = x[((size_t)(2 * bp + 1) << 12) + v];
    x0[(v << 7) + 2 * bp] = e;
    x0[(v << 7) + 2 * bp + 1] = o;
    mir[(v << 6) + bp] = packbf(e, o);
}

// ---------------- prepack W2/W3 -> bf16 [k][fo][fi]
__global__ __launch_bounds__(256) void k_packw(const float* __restrict__ w2, const float* __restrict__ w3,
        unsigned short* __restrict__ wb2, unsigned short* __restrict__ wb3) {
    int i = blockIdx.x * 256 + threadIdx.x;
    if (i < 51200) {        // 25*64*32
        int k = i >> 11, rem = i & 2047, fo = rem >> 5, fi = rem & 31;
        wb2[i] = (unsigned short)f2bfu(w2[(size_t)(fi * K_ + k) * 64 + fo]);
    }
    if (i < 102400) {       // 25*64*64
        int k = i >> 12, rem = i & 4095, fo = rem >> 6, fi = rem & 63;
        wb3[i] = (unsigned short)f2bfu(w3[(size_t)(fi * K_ + k) * 64 + fo]);
    }
}

// ---------------- layer-1 SpMM via bf16 mirror: thread owns (v, slab of 4 dwords = 8 b)
__global__ __launch_bounds__(256) void k_spmm1m(const int* __restrict__ cols, const float* __restrict__ vals,
        const unsigned* __restrict__ mirPrev, const float* __restrict__ prevF,
        float* __restrict__ nextF, unsigned* __restrict__ mirOut, int two) {
    int i = blockIdx.x * 256 + threadIdx.x;   // 65536: v = i>>4, sl = i&15
    int v = i >> 4, sl = i & 15;
    int base = v * DEG_;
    int moff = sl << 2;
    float4 eA = make_float4(0.f, 0.f, 0.f, 0.f), oA = eA, eB = eA, oB = eA;
#pragma unroll
    for (int d = 0; d < 8; ++d) {
        {
            float w = vals[base + d];
            uint4 m = *(const uint4*)(mirPrev + ((size_t)cols[base + d] << 6) + moff);
            eA = f4ma(w, mevens(m), eA); oA = f4ma(w, modds(m), oA);
        }
        {
            float w = vals[base + 8 + d];
            uint4 m = *(const uint4*)(mirPrev + ((size_t)cols[base + 8 + d] << 6) + moff);
            eB = f4ma(w, mevens(m), eB); oB = f4ma(w, modds(m), oB);
        }
    }
    float4 e = f4add(eA, eB), o = f4add(oA, oB);
    float4 f0 = make_float4(e.x, o.x, e.y, o.y);
    float4 f1 = make_float4(e.z, o.z, e.w, o.w);
    size_t sidx = ((size_t)v << 7) + (sl << 3);
    if (two) {
        float4 p0 = *(const float4*)(prevF + sidx), p1 = *(const float4*)(prevF + sidx + 4);
        f0 = f4sub2(f0, p0); f1 = f4sub2(f1, p1);
    }
    *(float4*)(nextF + sidx) = f0;
    *(float4*)(nextF + sidx + 4) = f1;
    *(uint4*)(mirOut + ((size_t)v << 6) + moff) =
        make_uint4(packbf(f0.x, f0.y), packbf(f0.z, f0.w), packbf(f1.x, f1.y), packbf(f1.z, f1.w));
}

// ---------------- SpMM (layers 2/3) gathering from bf16 mirror; fp32 prev/next in-place
template<int LOGF2>
__global__ __launch_bounds__(256) void k_spmm4m(const int* __restrict__ cols, const float* __restrict__ vals,
        const unsigned* __restrict__ mirPrev, float* __restrict__ st,
        unsigned* __restrict__ mirOut, int two) {
    constexpr int SL = LOGF2 + 2;                 // threads per (v, slab)
    constexpr int MSTR = 1 << (LOGF2 + 7);        // mirror v-stride (dwords)
    int xcd = blockIdx.x & 7, q = blockIdx.x >> 3;
    int v = __builtin_amdgcn_readfirstlane((q << (8 - SL)) + (threadIdx.x >> SL));
    int l = threadIdx.x & ((1 << SL) - 1);
    int cc = (xcd << SL) + l;
    int fi2 = cc >> 5, b0 = (cc & 31) << 2;
    int base = v * DEG_;
    int moff = (fi2 << 7) + b0;
    float4 eA = make_float4(0.f, 0.f, 0.f, 0.f), eB = eA, oA = eA, oB = eA;
#pragma unroll
    for (int d = 0; d < 8; ++d) {
        {
            float w = vals[base + d];
            uint4 m = *(const uint4*)(mirPrev + (size_t)cols[base + d] * MSTR + moff);
            eA = f4ma(w, mevens(m), eA); oA = f4ma(w, modds(m), oA);
        }
        {
            float w = vals[base + 8 + d];
            uint4 m = *(const uint4*)(mirPrev + (size_t)cols[base + 8 + d] * MSTR + moff);
            eB = f4ma(w, mevens(m), eB); oB = f4ma(w, modds(m), oB);
        }
    }
    float4 e = f4add(eA, eB), o = f4add(oA, oB);
    size_t sidx = ((size_t)v << (LOGF2 + 8)) + (fi2 << 8) + b0;
    if (two) {
        float4 pe = *(const float4*)(st + sidx), po = *(const float4*)(st + sidx + 128);
        e = f4sub2(e, pe); o = f4sub2(o, po);
    }
    *(float4*)(st + sidx) = e;
    *(float4*)(st + sidx + 128) = o;
    *(uint4*)(mirOut + (size_t)v * MSTR + moff) =
        make_uint4(packbf(e.x, o.x), packbf(e.y, o.y), packbf(e.z, o.z), packbf(e.w, o.w));
}

// ---------------- layer 1 projection (Fin=1, Fout=32) + bias + relu + pool4 (+ bf16 mirror)
__global__ __launch_bounds__(256) void k_proj1_pool(const float* __restrict__ basis,
        const float* __restrict__ W1, const float* __restrict__ b1, float* __restrict__ pool1,
        unsigned* __restrict__ mir) {
    int half = blockIdx.y;
    int i = blockIdx.x * 256 + threadIdx.x;   // i = g*128 + b
    int g = i >> 7, b = i & 127;
    const float* wbase = W1 + half * 16;
#define P1_DM(j) float4 M##j = make_float4(-1e30f, -1e30f, -1e30f, -1e30f);
    R4(P1_DM)
#undef P1_DM
    for (int r = 0; r < 4; ++r) {
        const float* bp = basis + (((size_t)(4 * g + r) << 7) + b);
#define P1_DC(j) float4 C##j = make_float4(0.f, 0.f, 0.f, 0.f);
        R4(P1_DC)
#undef P1_DC
#pragma unroll 5
        for (int k = 0; k < K_; ++k) {
            float tv = bp[(size_t)k * 524288];
            const float4* w = (const float4*)(wbase + k * 32);
#define P1_FM(j) C##j = f4ma(tv, w[j], C##j);
            R4(P1_FM)
#undef P1_FM
        }
#define P1_MX(j) M##j = f4max(M##j, C##j);
        R4(P1_MX)
#undef P1_MX
    }
    float* op = pool1 + ((size_t)g << 12) + ((size_t)half << 11) + b;
    unsigned* mp = mir + ((size_t)g << 11) + ((size_t)half << 10) + b;
    const float* bb = b1 + half * 16;
#define P1_ST(j) { \
    float e0 = fmaxf(M##j.x + bb[4*j+0], 0.f); \
    float o0 = fmaxf(M##j.y + bb[4*j+1], 0.f); \
    float e1 = fmaxf(M##j.z + bb[4*j+2], 0.f); \
    float o1 = fmaxf(M##j.w + bb[4*j+3], 0.f); \
    op[(4*j+0)*128] = e0; op[(4*j+1)*128] = o0; \
    op[(4*j+2)*128] = e1; op[(4*j+3)*128] = o1; \
    mp[(2*j+0)*128] = packbf(e0, o0); \
    mp[(2*j+1)*128] = packbf(e1, o1); }
    R4(P1_ST)
#undef P1_ST
}

// ---------------- layer-2 chunk projection via MFMA: one wave = 16 b x 64 fo, K=5kk*32fi
__global__ __launch_bounds__(256) void k_proj_l2m(const unsigned* __restrict__ mir, size_t slotH,
        const uint4* __restrict__ wb, float* __restrict__ acc, int k0, int init,
        const float* __restrict__ bias) {
    int wid = blockIdx.x * 4 + (threadIdx.x >> 6);   // 8192 waves
    int lane = threadIdx.x & 63;
    int lm = lane & 15, lg = lane >> 4;
    int v = wid >> 3, b0 = (wid & 7) << 4;
    float* ap = acc + ((size_t)v << 13) + b0 + (lg << 2);
    f32x4 C0, C1, C2, C3;
    if (init) {
        float q0 = bias[lm], q1 = bias[16 + lm], q2 = bias[32 + lm], q3 = bias[48 + lm];
        C0 = f32x4{q0, q0, q0, q0}; C1 = f32x4{q1, q1, q1, q1};
        C2 = f32x4{q2, q2, q2, q2}; C3 = f32x4{q3, q3, q3, q3};
    } else {
        C0 = *(const f32x4*)(ap + (size_t)lm * 128);
        C1 = *(const f32x4*)(ap + (size_t)(16 + lm) * 128);
        C2 = *(const f32x4*)(ap + (size_t)(32 + lm) * 128);
        C3 = *(const f32x4*)(ap + (size_t)(48 + lm) * 128);
    }
    const unsigned* mp0 = mir + ((size_t)v << 11) + (lg << 9) + b0 + lm;
#pragma unroll
    for (int kk = 0; kk < 5; ++kk) {
        const unsigned* mp = mp0 + (size_t)kk * slotH;
        uint4 a = make_uint4(mp[0], mp[128], mp[256], mp[384]);
        int kb = (k0 + kk) << 6;
        uint4 w0 = wb[(kb + lm) * 4 + lg];
        uint4 w1 = wb[(kb + 16 + lm) * 4 + lg];
        uint4 w2 = wb[(kb + 32 + lm) * 4 + lg];
        uint4 w3 = wb[(kb + 48 + lm) * 4 + lg];
        C0 = mfma_bf(a, w0, C0);
        C1 = mfma_bf(a, w1, C1);
        C2 = mfma_bf(a, w2, C2);
        C3 = mfma_bf(a, w3, C3);
    }
    *(f32x4*)(ap + (size_t)lm * 128) = C0;
    *(f32x4*)(ap + (size_t)(16 + lm) * 128) = C1;
    *(f32x4*)(ap + (size_t)(32 + lm) * 128) = C2;
    *(f32x4*)(ap + (size_t)(48 + lm) * 128) = C3;
}

// ---------------- layer-3 chunk projection via MFMA: Fin=64 -> 2 K-steps per kk
__global__ __launch_bounds__(256) void k_proj_l3m(const unsigned* __restrict__ mir, size_t slotH,
        const uint4* __restrict__ wb, float* __restrict__ acc, int k0, int init,
        const float* __restrict__ bias, int finalrelu) {
    int wid = blockIdx.x * 4 + (threadIdx.x >> 6);   // 2048 waves
    int lane = threadIdx.x & 63;
    int lm = lane & 15, lg = lane >> 4;
    int v = wid >> 3, b0 = (wid & 7) << 4;
    float* ap = acc + ((size_t)v << 13) + b0 + (lg << 2);
    f32x4 C0, C1, C2, C3;
    if (init) {
        float q0 = bias[lm], q1 = bias[16 + lm], q2 = bias[32 + lm], q3 = bias[48 + lm];
        C0 = f32x4{q0, q0, q0, q0}; C1 = f32x4{q1, q1, q1, q1};
        C2 = f32x4{q2, q2, q2, q2}; C3 = f32x4{q3, q3, q3, q3};
    } else {
        C0 = *(const f32x4*)(ap + (size_t)lm * 128);
        C1 = *(const f32x4*)(ap + (size_t)(16 + lm) * 128);
        C2 = *(const f32x4*)(ap + (size_t)(32 + lm) * 128);
        C3 = *(const f32x4*)(ap + (size_t)(48 + lm) * 128);
    }
    const unsigned* mp0 = mir + ((size_t)v << 12) + b0 + lm;
#pragma unroll
    for (int kk = 0; kk < 5; ++kk) {
        const unsigned* mp = mp0 + (size_t)kk * slotH;
        int kb = (k0 + kk) << 6;
#pragma unroll
        for (int ks = 0; ks < 2; ++ks) {
            const unsigned* mk = mp + (size_t)((ks << 4) + (lg << 2)) * 128;
            uint4 a = make_uint4(mk[0], mk[128], mk[256], mk[384]);
            int wof = (ks << 2) + lg;
            uint4 w0 = wb[(kb + lm) * 8 + wof];
            uint4 w1 = wb[(kb + 16 + lm) * 8 + wof];
            uint4 w2 = wb[(kb + 32 + lm) * 8 + wof];
            uint4 w3 = wb[(kb + 48 + lm) * 8 + wof];
            C0 = mfma_bf(a, w0, C0);
            C1 = mfma_bf(a, w1, C1);
            C2 = mfma_bf(a, w2, C2);
            C3 = mfma_bf(a, w3, C3);
        }
    }
    if (finalrelu) {
#pragma unroll
        for (int r = 0; r < 4; ++r) {
            C0[r] = fmaxf(C0[r], 0.f); C1[r] = fmaxf(C1[r], 0.f);
            C2[r] = fmaxf(C2[r], 0.f); C3[r] = fmaxf(C3[r], 0.f);
        }
    }
    *(f32x4*)(ap + (size_t)lm * 128) = C0;
    *(f32x4*)(ap + (size_t)(16 + lm) * 128) = C1;
    *(f32x4*)(ap + (size_t)(32 + lm) * 128) = C2;
    *(f32x4*)(ap + (size_t)(48 + lm) * 128) = C3;
}

// ---------------- relu + pool4 + bf16 mirror (layer2 acc -> layer3 T0 state + mirror slot0)
__global__ __launch_bounds__(256) void k_relu_pool_m(const float* __restrict__ acc,
        float* __restrict__ pool, unsigned* __restrict__ mir) {
    int i = blockIdx.x * 256 + threadIdx.x;   // g*4096 + fi2*128 + b
    int g = i >> 12, fi2 = (i >> 7) & 31, b = i & 127;
    const float* ap = acc + (((size_t)g << 2) << 13) + (fi2 << 8) + b;
    float me = 0.f, mo = 0.f;
#pragma unroll
    for (int r = 0; r < 4; ++r) {
        me = fmaxf(me, ap[0]); mo = fmaxf(mo, ap[128]);
        ap += 8192;
    }
    size_t po = ((size_t)g << 13) + (fi2 << 8) + b;
    pool[po] = me; pool[po + 128] = mo;
    mir[i] = packbf(me, mo);
}

// ---------------- FC1 partials: rowsplit 64, 8 b's per thread, 2048 blocks (round-13 form)
__global__ __launch_bounds__(256) void k_fc1_part(const float* __restrict__ t3, const float* __restrict__ w,
                           float* __restrict__ part) {
    int blk = blockIdx.x;
    int bg = blk >> 7;
    int rs = (blk >> 1) & 63;
    int j = ((blk & 1) << 8) + threadIdx.x;
    int b0 = bg << 3;
    float a0=0.f,a1=0.f,a2=0.f,a3=0.f,a4=0.f,a5=0.f,a6=0.f,a7=0.f;
    int r0 = rs << 8;
#pragma unroll 4
    for (int row = r0; row < r0 + 256; ++row) {
        float wv = w[((size_t)row << 9) + j];
        const float4* tp = (const float4*)(t3 + ((size_t)row << 7) + b0);
        float4 t0 = tp[0], t1 = tp[1];
        a0 = fmaf(t0.x, wv, a0);
        a1 = fmaf(t0.y, wv, a1);
        a2 = fmaf(t0.z, wv, a2);
        a3 = fmaf(t0.w, wv, a3);
        a4 = fmaf(t1.x, wv, a4);
        a5 = fmaf(t1.y, wv, a5);
        a6 = fmaf(t1.z, wv, a6);
        a7 = fmaf(t1.w, wv, a7);
    }
    float* pp = part + (((size_t)(rs << 7) + b0) << 9) + j;
    pp[0*512]=a0; pp[1*512]=a1; pp[2*512]=a2; pp[3*512]=a3;
    pp[4*512]=a4; pp[5*512]=a5; pp[6*512]=a6; pp[7*512]=a7;
}

__global__ __launch_bounds__(256) void k_fc1_red(const float* __restrict__ part, const float* __restrict__ bias,
                          float* __restrict__ h) {
    int i = blockIdx.x * 256 + threadIdx.x;   // i = b*512 + j
    float a = bias[i & 511];
#pragma unroll 8
    for (int rs = 0; rs < 64; ++rs) a += part[((size_t)rs << 16) + i];
    h[i] = a;
}

// ---------------- batchnorm stats over batch (biased var), store mean | inv_std
__global__ void k_bnstats(const float* __restrict__ h, float* __restrict__ mv) {
    __shared__ float s1[128], s2[128];
    int j = blockIdx.x, t = threadIdx.x;
    float v = h[(size_t)t * 512 + j];
    s1[t] = v; s2[t] = v * v;
    __syncthreads();
    for (int o = 64; o > 0; o >>= 1) {
        if (t < o) { s1[t] += s1[t + o]; s2[t] += s2[t + o]; }
        __syncthreads();
    }
    if (t == 0) {
        float m = s1[0] * (1.f / 128.f);
        float var = s2[0] * (1.f / 128.f) - m * m;
        mv[j] = m;
        mv[512 + j] = rsqrtf(var + 1e-5f);
    }
}

// ---------------- BN apply + relu + FC2 + log_softmax, one block per batch row
__global__ void k_head(const float* __restrict__ h, const float* __restrict__ mv,
                       const float* __restrict__ gamma, const float* __restrict__ beta,
                       const float* __restrict__ w2, const float* __restrict__ b2,
                       float* __restrict__ out) {
    __shared__ float hr[512];
    __shared__ float lg[16];
    int b = blockIdx.x, t = threadIdx.x;   // 64 threads
    for (int j = t; j < 512; j += 64) {
        float x = (h[(size_t)b * 512 + j] - mv[j]) * mv[512 + j] * gamma[j] + beta[j];
        hr[j] = fmaxf(x, 0.f);
    }
    __syncthreads();
    if (t < 10) {
        float a = b2[t];
        for (int j = 0; j < 512; ++j) a += hr[j] * w2[j * 10 + t];
        lg[t] = a;
    }
    __syncthreads();
    if (t == 0) {
        float mx = -1e30f;
        for (int q = 0; q < 10; ++q) mx = fmaxf(mx, lg[q]);
        float sum = 0.f;
        for (int q = 0; q < 10; ++q) sum += expf(lg[q] - mx);
        float ls = logf(sum) + mx;
        for (int q = 0; q < 10; ++q) out[b * 10 + q] = lg[q] - ls;
    }
}

extern "C" void kernel_launch(void* const* d_in, const int* in_sizes, int n_in,
                              void* d_out, int out_size, void* d_ws, size_t ws_size,
                              hipStream_t stream) {
    (void)in_sizes; (void)n_in; (void)out_size; (void)ws_size;
    const float* x      = (const float*)d_in[0];
    const int*   l0cols = (const int*)d_in[2];
    const float* l0vals = (const float*)d_in[3];
    const int*   l2cols = (const int*)d_in[5];
    const float* l2vals = (const float*)d_in[6];
    const int*   l4cols = (const int*)d_in[8];
    const float* l4vals = (const float*)d_in[9];
    const float* w1   = (const float*)d_in[10];
    const float* b1   = (const float*)d_in[11];
    const float* w2   = (const float*)d_in[12];
    const float* b2   = (const float*)d_in[13];
    const float* w3   = (const float*)d_in[14];
    const float* b3   = (const float*)d_in[15];
    const float* fc1w = (const float*)d_in[16];
    const float* fc1b = (const float*)d_in[17];
    const float* gam  = (const float*)d_in[18];
    const float* bet  = (const float*)d_in[19];
    const float* fc2w = (const float*)d_in[20];
    const float* fc2b = (const float*)d_in[21];
    float* out = (float*)d_out;

    const size_t S1 = 4096 * 128;
    const size_t S2 = 1024 * 4096;
    const size_t S3 = 256 * 8192;

    float* ws = (float*)d_ws;
    float* basis1 = ws;                                  // 25 slots of S1 (layer-1, fp32)
    float* st2A   = ws + 25 * S1;                        // layer-2 fp32 state, parity 0
    float* st2B   = st2A + S2;                           // parity 1
    unsigned* mir2 = (unsigned*)(st2B + S2);             // 5 slots of S2/2 dwords (also mir3 ring)
    float* tailp  = (float*)(mir2 + 5 * (S2 / 2));
    float* h      = tailp;                               // 65536
    float* mv     = h + 65536;                           // 1024
    unsigned short* wb2 = (unsigned short*)(mv + 1024);  // 51200 bf16
    unsigned short* wb3 = wb2 + 51200;                   // 102400 bf16
    unsigned* mir1 = (unsigned*)(wb3 + 102400);          // 2 slots of S1/2 dwords
    float* acc2   = basis1;                              // alias: basis1 dead after proj1
    float* st3A   = st2A;                                // alias: 2*S3 == S2
    float* st3B   = st2A + S3;
    float* acc3   = st2B;                                // alias: layer-2 parity-1 dead
    unsigned* mir3 = mir2;
    float* part   = basis1;                              // alias: acc2 dead by then

    k_packw<<<400, 256, 0, stream>>>(w2, w3, wb2, wb3);

    // ---------------- Layer 1: V=4096, bf16-mirror gather, fp32 basis kept ----------------
    k_transpose_xm<<<1024, 256, 0, stream>>>(x, basis1, mir1);
    for (int k = 1; k < 25; ++k) {
        const float* prevF = (k >= 2) ? basis1 + (size_t)(k - 2) * S1 : basis1;
        float* nextF = basis1 + (size_t)k * S1;
        k_spmm1m<<<256, 256, 0, stream>>>(l0cols, l0vals,
            mir1 + (size_t)((k - 1) & 1) * (S1 / 2), prevF, nextF,
            mir1 + (size_t)(k & 1) * (S1 / 2), k >= 2 ? 1 : 0);
    }
    k_proj1_pool<<<dim3(512, 2), 256, 0, stream>>>(basis1, w1, b1, st2A, mir2);

    // ---------------- Layer 2: V=1024, bf16-mirror gather, fp32 parity ping-pong ----------------
    {
        float* s2[2] = {st2A, st2B};
        int cs = 0;
        for (int k = 0; k < 25; ++k) {
            if (k >= 1) {
                k_spmm4m<4><<<2048, 256, 0, stream>>>(l2cols, l2vals,
                    mir2 + (size_t)((k - 1) % 5) * (S2 / 2), s2[k & 1],
                    mir2 + (size_t)(k % 5) * (S2 / 2), k >= 2 ? 1 : 0);
            }
            if (k - cs + 1 == 5) {
                k_proj_l2m<<<2048, 256, 0, stream>>>(mir2, S2 / 2, (const uint4*)wb2, acc2, cs,
                                                     cs == 0 ? 1 : 0, b2);
                cs = k + 1;
            }
        }
    }
    k_relu_pool_m<<<4096, 256, 0, stream>>>(acc2, st3A, mir3);

    // ---------------- Layer 3: V=256, bf16-mirror gather, fp32 parity ping-pong ----------------
    {
        float* s3[2] = {st3A, st3B};
        int cs = 0;
        for (int k = 0; k < 25; ++k) {
            if (k >= 1) {
                k_spmm4m<5><<<1024, 256, 0, stream>>>(l4cols, l4vals,
                    mir3 + (size_t)((k - 1) % 5) * (S3 / 2), s3[k & 1],
                    mir3 + (size_t)(k % 5) * (S3 / 2), k >= 2 ? 1 : 0);
            }
            if (k - cs + 1 == 5) {
                k_proj_l3m<<<512, 256, 0, stream>>>(mir3, S3 / 2, (const uint4*)wb3, acc3, cs,
                                                    cs == 0 ? 1 : 0, b3, cs == 20 ? 1 : 0);
                cs = k + 1;
            }
        }
    }

    // ---------------- FC1 + BN + FC2 + log_softmax ----------------
    k_fc1_part<<<2048, 256, 0, stream>>>(acc3, fc1w, part);
    k_fc1_red<<<256, 256, 0, stream>>>(part, fc1b, h);
    k_bnstats<<<512, 128, 0, stream>>>(h, mv);
    k_head<<<128, 64, 0, stream>>>(h, mv, gam, bet, fc2w, fc2b, out);
}